// Round 10
// baseline (168.804 us; speedup 1.0000x reference)
//
#include <hip/hip_runtime.h>

typedef short short8 __attribute__((ext_vector_type(8)));
typedef float f32x4 __attribute__((ext_vector_type(4)));
typedef unsigned int uint4v __attribute__((ext_vector_type(4)));

#define EPS_NUMER_F 1e-8f
#define EPS_D2_F 1e-12f

#define BB 128
#define TT 128
#define DD 1024
#define CHW 3072
#define NC 10
#define MM (BB * TT)
#define NT 48              // CHW / 64 K-tiles

#define GLOAD_LDS16(g, l)                                              \
  __builtin_amdgcn_global_load_lds(                                    \
      (const __attribute__((address_space(1))) void*)(g),              \
      (__attribute__((address_space(3))) void*)(l), 16, 0, 0)

#define DS_READ_B128(dst_, off_) \
  asm volatile("ds_read_b128 %0, %1" : "=v"(dst_) : "v"(off_))
#define DS_WRITE_B128(off_, val_) \
  asm volatile("ds_write_b128 %0, %1" :: "v"(off_), "v"(val_))
#define GLB_LOAD_X4(dst_, voff_, imm_) \
  asm volatile("global_load_dwordx4 %0, %1, %2 offset:" #imm_ \
               : "=v"(dst_) : "v"(voff_), "s"(xbase))
#define SCHED_FENCE() __builtin_amdgcn_sched_barrier(0)

static __device__ __forceinline__ unsigned lds_addr(const void* p) {
  return (unsigned)(unsigned long long)(const __attribute__((address_space(3))) void*)p;
}
static __device__ __forceinline__ unsigned cvt2(float lo, float hi) {
  unsigned r;
  asm("v_cvt_pk_bf16_f32 %0, %1, %2" : "=v"(r) : "v"(lo), "v"(hi));
  return r;
}

static __device__ __forceinline__ short f2bf(float x) {
  unsigned int u = __float_as_uint(x);
  u = (u + 0x7fffu + ((u >> 16) & 1u)) >> 16;
  return (short)u;
}
static __device__ __forceinline__ float bf2f(short x) {
  return __uint_as_float(((unsigned int)(unsigned short)x) << 16);
}

// ---------------------------------------------------------------------------
// W_fe (3072 x 1024 f32, K x N) -> Wt (1024 x 3072 bf16, N x K)
// ---------------------------------------------------------------------------
__global__ __launch_bounds__(256) void k_transpose_w(const float* __restrict__ W,
                                                     short* __restrict__ Wt) {
  __shared__ float tile[32][33];
  const int n0 = blockIdx.x * 32;
  const int k0 = blockIdx.y * 32;
  const int tx = threadIdx.x & 31;
  const int ty = threadIdx.x >> 5;
#pragma unroll
  for (int i = 0; i < 32; i += 8)
    tile[ty + i][tx] = W[(size_t)(k0 + ty + i) * DD + (n0 + tx)];
  __syncthreads();
#pragma unroll
  for (int i = 0; i < 32; i += 8)
    Wt[(size_t)(n0 + ty + i) * CHW + (k0 + tx)] = f2bf(tile[tx][ty + i]);
}

// ---------------------------------------------------------------------------
// Fused 128x128 2-phase GEMM, 2 blocks/CU: F = bf16(X) @ Wt^T + b.  BK=64,
// 512 thr (8 waves 2Mx4N, per-wave 64x32).  LDS 64 KiB -> occupancy 2/CU:
// co-resident block fills SIMD while this one waits at barriers (m114/m97).
// Counted vmcnt(2) once per tile; asm ds_read/glb_load; swizzled LDS.
// ---------------------------------------------------------------------------
__global__ __launch_bounds__(512, 4) void k_gemm_2cu(const float* __restrict__ X,
                                                     const short* __restrict__ Wt,
                                                     const float* __restrict__ bias,
                                                     short* __restrict__ F) {
  __shared__ short As[2][128 * 64];
  __shared__ short Bs[2][128 * 64];

  // 1024 blocks, 8 XCDs, 128 ids/XCD; consecutive ids share bm row-panel.
  const int bid = blockIdx.x;
  const int id = (bid & 7) * 128 + (bid >> 3);
  const int bm = (id >> 3) << 7;   // 128 row tiles
  const int bn = (id & 7) << 7;    // 8 col tiles

  const int tid = threadIdx.x;
  const int lane = tid & 63;
  const int wid = tid >> 6;        // 0..7
  const int wr = wid >> 2;         // 0..1 -> rows wr*64
  const int wc = wid & 3;          // 0..3 -> cols wc*32

  // ---- B staging: 16 chunks of 1024B (8 rows each); wave w takes chunks
  // w and 8+w.  lane: row += lane>>3, pre-swizzled src slot (lane&7)^(lane>>3).
  const int srow = lane >> 3;
  const int sslot = (lane & 7) ^ (lane >> 3);
  const short* bSrc = Wt + (size_t)(bn + srow) * CHW + sslot * 8;

#define STAGE_B(T_) do {                                                     \
    GLOAD_LDS16(bSrc + (size_t)(wid * 8) * CHW + (T_) * 64,                  \
                &Bs[(T_) & 1][wid * 512]);                                   \
    GLOAD_LDS16(bSrc + (size_t)(64 + wid * 8) * CHW + (T_) * 64,            \
                &Bs[(T_) & 1][(8 + wid) * 512]);                             \
  } while (0)

  // ---- A staging: half h covers rows h*64 + wid*8 + (lane>>3); lane reads
  // 8 f32 (32B contiguous) at col (lane&7)*8; cvt -> 1 ds_write_b128 at
  // swizzled slot (lane&7)^(row&7) where row&7 == lane>>3.
  const int arow0 = wid * 8 + (lane >> 3);
  const unsigned long long xbase = (unsigned long long)X;
  unsigned voffA0 = (unsigned)(((size_t)(bm + arow0) * CHW + (lane & 7) * 8) * 4);
  unsigned voffA1 = (unsigned)(((size_t)(bm + 64 + arow0) * CHW + (lane & 7) * 8) * 4);
  const unsigned aposb = (unsigned)(((lane & 7) ^ (lane >> 3)) * 16);

  f32x4 ra[2], rb[2];

#define LOAD_A() do {                                                        \
    GLB_LOAD_X4(ra[0], voffA0, 0);  GLB_LOAD_X4(ra[1], voffA0, 16);          \
    GLB_LOAD_X4(rb[0], voffA1, 0);  GLB_LOAD_X4(rb[1], voffA1, 16);          \
  } while (0)
#define ADV_A() do { voffA0 += 256; voffA1 += 256; } while (0)
#define WRITE_A(T_) do {                                                     \
    unsigned off_ = ((T_) & 1) ? 16384u : 0u;                                \
    uint4v w_;                                                               \
    w_.x = cvt2(ra[0].x, ra[0].y); w_.y = cvt2(ra[0].z, ra[0].w);            \
    w_.z = cvt2(ra[1].x, ra[1].y); w_.w = cvt2(ra[1].z, ra[1].w);            \
    DS_WRITE_B128(aWr0 + off_, w_);                                          \
    w_.x = cvt2(rb[0].x, rb[0].y); w_.y = cvt2(rb[0].z, rb[0].w);            \
    w_.z = cvt2(rb[1].x, rb[1].y); w_.w = cvt2(rb[1].z, rb[1].w);            \
    DS_WRITE_B128(aWr1 + off_, w_);                                          \
  } while (0)

  // fragment read addressing (swizzled); LDS row = 64 shorts = 128 B
  const int fr = lane & 15;
  const int sl = lane >> 4;
  const int slotk0 = sl ^ (lane & 7);
  const int slotk1 = (4 + sl) ^ (lane & 7);
  const int arow = wr * 64 + fr;
  const int brow = wc * 32 + fr;

  const unsigned aBase0 = lds_addr(&As[0][0]);
  const unsigned bBase0 = lds_addr(&Bs[0][0]);
  const unsigned aWr0 = aBase0 + (unsigned)(arow0 * 128) + aposb;
  const unsigned aWr1 = aWr0 + 64u * 128u;

  short8 bqf[4];   // B frags (ni 0..1 x ks 0..1), read at p0, held both phases
  short8 aq[4];    // A frags for current k-slot (mi 0..3)
  f32x4 acc[4][2] = {};

#define READ_B4(bb_) do {                                                    \
    DS_READ_B128(bqf[0], (bb_) + (unsigned)((brow     ) * 128 + slotk0 * 16)); \
    DS_READ_B128(bqf[1], (bb_) + (unsigned)((brow     ) * 128 + slotk1 * 16)); \
    DS_READ_B128(bqf[2], (bb_) + (unsigned)((brow + 16) * 128 + slotk0 * 16)); \
    DS_READ_B128(bqf[3], (bb_) + (unsigned)((brow + 16) * 128 + slotk1 * 16)); \
  } while (0)
#define READ_AK(ab_, slot_) do {                                             \
    DS_READ_B128(aq[0], (ab_) + (unsigned)((arow     ) * 128 + (slot_) * 16)); \
    DS_READ_B128(aq[1], (ab_) + (unsigned)((arow + 16) * 128 + (slot_) * 16)); \
    DS_READ_B128(aq[2], (ab_) + (unsigned)((arow + 32) * 128 + (slot_) * 16)); \
    DS_READ_B128(aq[3], (ab_) + (unsigned)((arow + 48) * 128 + (slot_) * 16)); \
  } while (0)
#define MFMA8(ks_) do {                                                      \
    _Pragma("unroll")                                                        \
    for (int mi = 0; mi < 4; ++mi)                                           \
      _Pragma("unroll")                                                      \
      for (int ni = 0; ni < 2; ++ni)                                         \
        acc[mi][ni] = __builtin_amdgcn_mfma_f32_16x16x32_bf16(               \
            aq[mi], bqf[ni * 2 + (ks_)], acc[mi][ni], 0, 0, 0);              \
  } while (0)

  // ---- prologue: A(0):4, B(0):2, B(1):2 -> vmcnt(2) drains A(0)+B(0);
  // write A(0); load A(1) -> queue [B(1):2, A(1):4]; voff -> tile 2.
  LOAD_A();
  STAGE_B(0);
  STAGE_B(1);
  SCHED_FENCE();
  asm volatile("s_waitcnt vmcnt(2)");
  SCHED_FENCE();
  WRITE_A(0);
  ADV_A();
  LOAD_A();
  ADV_A();
  asm volatile("s_waitcnt lgkmcnt(0)");
  SCHED_FENCE();
  __builtin_amdgcn_s_barrier();

  for (int T = 0; T < NT; ++T) {
    const unsigned ab = aBase0 + ((T & 1) ? 16384u : 0u);
    const unsigned bb = bBase0 + ((T & 1) ? 16384u : 0u);

    // ---- p0: read all B frags + A k0; pure compute phase.
    READ_B4(bb);
    READ_AK(ab, slotk0);
    SCHED_FENCE();
    __builtin_amdgcn_s_barrier();
    asm volatile("s_waitcnt lgkmcnt(0)");
    SCHED_FENCE();
    __builtin_amdgcn_s_setprio(1);
    MFMA8(0);
    __builtin_amdgcn_s_setprio(0);
    SCHED_FENCE();
    __builtin_amdgcn_s_barrier();

    // ---- p1: read A k1; stage B(T+2) (safe: all B reads done at p0);
    // vmcnt(2) drains B(T+1)+A(T+1), leaves B(T+2); write A(T+1); load A(T+2).
    READ_AK(ab, slotk1);
    if (T + 2 < NT) {
      STAGE_B(T + 2);
      SCHED_FENCE();
      asm volatile("s_waitcnt vmcnt(2)");
      SCHED_FENCE();
    } else if (T + 1 < NT) {
      SCHED_FENCE();
      asm volatile("s_waitcnt vmcnt(0)");
      SCHED_FENCE();
    }
    if (T + 1 < NT) WRITE_A(T + 1);
    if (T + 2 < NT) {
      LOAD_A();
      ADV_A();
    }
    SCHED_FENCE();
    __builtin_amdgcn_s_barrier();
    asm volatile("s_waitcnt lgkmcnt(0)");   // drains A-k1 reads + A writes
    SCHED_FENCE();
    __builtin_amdgcn_s_setprio(1);
    MFMA8(1);
    __builtin_amdgcn_s_setprio(0);
    SCHED_FENCE();
    __builtin_amdgcn_s_barrier();
  }

  // epilogue: C/D layout col = lane&15, row = (lane>>4)*4 + q
  const int cc = lane & 15;
  const int crr = sl << 2;
#pragma unroll
  for (int ni = 0; ni < 2; ++ni) {
    int col = bn + wc * 32 + ni * 16 + cc;
    float bv = bias[col];
#pragma unroll
    for (int mi = 0; mi < 4; ++mi) {
      int row0 = bm + wr * 64 + mi * 16 + crr;
#pragma unroll
      for (int q = 0; q < 4; ++q)
        F[(size_t)(row0 + q) * DD + col] = f2bf(acc[mi][ni][q] + bv);
    }
  }
#undef READ_B4
#undef READ_AK
#undef MFMA8
#undef STAGE_B
#undef LOAD_A
#undef ADV_A
#undef WRITE_A
}

// ---------------------------------------------------------------------------
// Kernel 3: per (batch, t-half): Gram via MFMA -> d2 -> sims -> causal numer
// -> pow/normalize -> out.
// ---------------------------------------------------------------------------
__global__ __launch_bounds__(256) void k_batch_sims(const short* __restrict__ F,
                                                    const float* __restrict__ teach,
                                                    const float* __restrict__ cptr,
                                                    const float* __restrict__ gptr,
                                                    float* __restrict__ out) {
  __shared__ short ftile[128][40];
  __shared__ float simsT[64][129];
  __shared__ float sqv[128];
  __shared__ float sqp[256];
  __shared__ float teach_s[128][NC];
  __shared__ float numer[64][NC];
  __shared__ float rsum[64];

  const int b = blockIdx.x >> 1;
  const int half = blockIdx.x & 1;
  const int tid = threadIdx.x;
  const int lane = tid & 63;
  const int w = tid >> 6;
  const size_t fbase = (size_t)b * TT * DD;

  for (int idx = tid; idx < TT * NC; idx += 256)
    teach_s[idx / NC][idx % NC] = teach[(size_t)b * TT * NC + idx];

  {
    int row = tid >> 1;
    int kh = (tid & 1) << 9;
    const short* fp = F + fbase + (size_t)row * DD + kh;
    float s = 0.f;
    for (int k = 0; k < 512; k += 8) {
      short8 v = *reinterpret_cast<const short8*>(fp + k);
#pragma unroll
      for (int j = 0; j < 8; ++j) { float x = bf2f(v[j]); s += x * x; }
    }
    sqp[tid] = s;
  }
  __syncthreads();
  if (tid < 128) sqv[tid] = sqp[2 * tid] + sqp[2 * tid + 1];
  __syncthreads();

  f32x4 acc[2][4] = {};
  const int fr = lane & 15;
  const int fk = (lane >> 4) << 3;
  for (int k0 = 0; k0 < DD; k0 += 32) {
#pragma unroll
    for (int i = 0; i < 2; ++i) {
      int idx = tid + (i << 8);
      int row = idx >> 2;
      int kc = (idx & 3) << 3;
      short8 v = *reinterpret_cast<const short8*>(F + fbase + (size_t)row * DD + (k0 + kc));
      *reinterpret_cast<short8*>(&ftile[row][kc]) = v;
    }
    __syncthreads();
    short8 af[2], bfv[4];
#pragma unroll
    for (int mi = 0; mi < 2; ++mi)
      af[mi] = *reinterpret_cast<const short8*>(&ftile[w * 32 + mi * 16 + fr][fk]);
#pragma unroll
    for (int ni = 0; ni < 4; ++ni)
      bfv[ni] = *reinterpret_cast<const short8*>(&ftile[half * 64 + ni * 16 + fr][fk]);
#pragma unroll
    for (int mi = 0; mi < 2; ++mi)
#pragma unroll
      for (int ni = 0; ni < 4; ++ni)
        acc[mi][ni] = __builtin_amdgcn_mfma_f32_16x16x32_bf16(af[mi], bfv[ni], acc[mi][ni], 0, 0, 0);
    __syncthreads();
  }

  const float c0 = cptr[0];
  const int cc = lane & 15;
  const int crr = (lane >> 4) << 2;
#pragma unroll
  for (int mi = 0; mi < 2; ++mi) {
#pragma unroll
    for (int ni = 0; ni < 4; ++ni) {
#pragma unroll
      for (int q = 0; q < 4; ++q) {
        int s_g = w * 32 + mi * 16 + crr + q;
        int tl = ni * 16 + cc;
        int t_g = half * 64 + tl;
        float g = acc[mi][ni][q];
        float d2 = sqv[s_g] + sqv[t_g] - 2.0f * g;
        d2 = fmaxf(d2, EPS_D2_F);
        float dist = sqrtf(sqrtf(d2));
        simsT[tl][s_g] = (s_g < t_g) ? expf(-c0 * dist) : 0.0f;
      }
    }
  }
  __syncthreads();

  const float gam = gptr[0];
  for (int idx = tid; idx < 64 * NC; idx += 256) {
    int tl = idx / NC, c = idx % NC;
    float s = 0.f;
#pragma unroll 4
    for (int si = 0; si < TT; ++si)
      s += simsT[tl][si] * teach_s[si][c];
    float v = EPS_NUMER_F + s;
    numer[tl][c] = (gam == 1.0f) ? v : powf(v, gam);
  }
  __syncthreads();
  if (tid < 64) {
    float s = 0.f;
#pragma unroll
    for (int c = 0; c < NC; ++c) s += numer[tid][c];
    rsum[tid] = s;
  }
  __syncthreads();
  for (int idx = tid; idx < 64 * NC; idx += 256) {
    int tl = idx / NC, c = idx % NC;
    int t_g = half * 64 + tl;
    float v = numer[tl][c] / rsum[tl];
    if (t_g == 0) v = EPS_NUMER_F;
    out[(size_t)b * TT * NC + (size_t)t_g * NC + c] = v;
  }
}

// ---------------------------------------------------------------------------
extern "C" void kernel_launch(void* const* d_in, const int* in_sizes, int n_in,
                              void* d_out, int out_size, void* d_ws, size_t ws_size,
                              hipStream_t stream) {
  const float* data = (const float*)d_in[1];
  const float* teach = (const float*)d_in[2];
  const float* Wfe = (const float*)d_in[3];
  const float* bfe = (const float*)d_in[4];
  const float* cp = (const float*)d_in[5];
  const float* gp = (const float*)d_in[6];
  float* outp = (float*)d_out;

  char* ws = (char*)d_ws;
  short* Wt = (short*)ws;                             // @0:   6.29 MB
  short* F = (short*)(ws + (size_t)8 * 1024 * 1024);  // @8MB: 33.55 MB

  k_transpose_w<<<dim3(DD / 32, CHW / 32), 256, 0, stream>>>(Wfe, Wt);
  k_gemm_2cu<<<dim3((MM / 128) * (DD / 128)), 512, 0, stream>>>(data, Wt, bfe, F);
  k_batch_sims<<<dim3(BB * 2), 256, 0, stream>>>(F, teach, cp, gp, outp);
}

// Round 11
// 158.631 us; speedup vs baseline: 1.0641x; 1.0641x over previous
//
#include <hip/hip_runtime.h>

typedef short short8 __attribute__((ext_vector_type(8)));
typedef float f32x4 __attribute__((ext_vector_type(4)));
typedef unsigned int uint4v __attribute__((ext_vector_type(4)));

#define EPS_NUMER_F 1e-8f
#define EPS_D2_F 1e-12f

#define BB 128
#define TT 128
#define DD 1024
#define CHW 3072
#define NC 10
#define MM (BB * TT)
#define NT 96              // CHW / 32 K-tiles

#define GLOAD_LDS16(g, l)                                              \
  __builtin_amdgcn_global_load_lds(                                    \
      (const __attribute__((address_space(1))) void*)(g),              \
      (__attribute__((address_space(3))) void*)(l), 16, 0, 0)

#define DS_READ_B128(dst_, off_) \
  asm volatile("ds_read_b128 %0, %1" : "=v"(dst_) : "v"(off_))
#define DS_WRITE_B128(off_, val_) \
  asm volatile("ds_write_b128 %0, %1" :: "v"(off_), "v"(val_))
#define GLB_LOAD_X4(dst_, voff_, imm_) \
  asm volatile("global_load_dwordx4 %0, %1, %2 offset:" #imm_ \
               : "=v"(dst_) : "v"(voff_), "s"(xbase))
#define SCHED_FENCE() __builtin_amdgcn_sched_barrier(0)

static __device__ __forceinline__ unsigned lds_addr(const void* p) {
  return (unsigned)(unsigned long long)(const __attribute__((address_space(3))) void*)p;
}
static __device__ __forceinline__ unsigned cvt2(float lo, float hi) {
  unsigned r;
  asm("v_cvt_pk_bf16_f32 %0, %1, %2" : "=v"(r) : "v"(lo), "v"(hi));
  return r;
}

static __device__ __forceinline__ short f2bf(float x) {
  unsigned int u = __float_as_uint(x);
  u = (u + 0x7fffu + ((u >> 16) & 1u)) >> 16;
  return (short)u;
}
static __device__ __forceinline__ float bf2f(short x) {
  return __uint_as_float(((unsigned int)(unsigned short)x) << 16);
}

// ---------------------------------------------------------------------------
// W_fe (3072 x 1024 f32, K x N) -> Wt (1024 x 3072 bf16, N x K)
// ---------------------------------------------------------------------------
__global__ __launch_bounds__(256) void k_transpose_w(const float* __restrict__ W,
                                                     short* __restrict__ Wt) {
  __shared__ float tile[32][33];
  const int n0 = blockIdx.x * 32;
  const int k0 = blockIdx.y * 32;
  const int tx = threadIdx.x & 31;
  const int ty = threadIdx.x >> 5;
#pragma unroll
  for (int i = 0; i < 32; i += 8)
    tile[ty + i][tx] = W[(size_t)(k0 + ty + i) * DD + (n0 + tx)];
  __syncthreads();
#pragma unroll
  for (int i = 0; i < 32; i += 8)
    Wt[(size_t)(n0 + ty + i) * CHW + (k0 + tx)] = f2bf(tile[tx][ty + i]);
}

// ---------------------------------------------------------------------------
// Fused 128x256 2-phase GEMM, BK=32, 2 blocks/CU: F = bf16(X) @ Wt^T + b.
// 512 thr (8 waves 2Mx4N, per-wave 64x64).  LDS 48 KiB -> 2 blocks/CU with
// UNCHANGED X reuse factor (4 N-tiles, same as the 256^2 r7 kernel).
// 64B LDS rows: swizzle slot' = sl ^ ((row>>1)&3) on write and read.
// Steady per-wave VMEM queue = 4: [B(T+1):2, A(T+1):2]; one vmcnt(2)/tile.
// ---------------------------------------------------------------------------
__global__ __launch_bounds__(512, 4) void k_gemm_2cu(const float* __restrict__ X,
                                                     const short* __restrict__ Wt,
                                                     const float* __restrict__ bias,
                                                     short* __restrict__ F) {
  __shared__ short As[2][128 * 32];   // 8 KiB / buf
  __shared__ short Bs[2][256 * 32];   // 16 KiB / buf

  // 512 blocks, 8 XCDs, 64 ids/XCD; 4 consecutive ids share bm (X L2 reuse).
  const int bid = blockIdx.x;
  const int id = (bid & 7) * 64 + (bid >> 3);
  const int bm = (id >> 2) << 7;   // 128 M-tiles
  const int bn = (id & 3) << 8;    // 4 N-tiles

  const int tid = threadIdx.x;
  const int lane = tid & 63;
  const int wid = tid >> 6;        // 0..7
  const int wr = wid >> 2;         // 0..1 -> rows wr*64
  const int wc = wid & 3;          // 0..3 -> cols wc*64

  // ---- B staging (gload_lds): 16 chunks of 1024B (16 rows of 64B); wave w
  // takes chunks w, 8+w.  lane: row += lane>>2, src slot (lane&3)^((lane>>3)&3).
  const int srow = lane >> 2;
  const int sslot = (lane & 3) ^ ((lane >> 3) & 3);
  const short* bSrc = Wt + (size_t)(bn + srow) * CHW + sslot * 8;

#define STAGE_B(T_) do {                                                     \
    GLOAD_LDS16(bSrc + (size_t)(wid * 16) * CHW + (T_) * 32,                 \
                &Bs[(T_) & 1][wid * 512]);                                   \
    GLOAD_LDS16(bSrc + (size_t)((8 + wid) * 16) * CHW + (T_) * 32,          \
                &Bs[(T_) & 1][(8 + wid) * 512]);                             \
  } while (0)

  // ---- A staging: thread t covers row t>>2 (0..127), f32 cols (t&3)*8..+8
  // (2 dwordx4); cvt -> 1 ds_write_b128 at slot' = (t&3) ^ ((t>>3)&3).
  const int arow0 = tid >> 2;
  const unsigned long long xbase = (unsigned long long)X;
  unsigned voffA = (unsigned)(((size_t)(bm + arow0) * CHW + (tid & 3) * 8) * 4);

  f32x4 ra[2];

#define LOAD_A() do {                                                        \
    GLB_LOAD_X4(ra[0], voffA, 0);  GLB_LOAD_X4(ra[1], voffA, 16);            \
    voffA += 128;                                                            \
  } while (0)
#define WRITE_A(T_) do {                                                     \
    unsigned off_ = ((T_) & 1) ? 8192u : 0u;                                 \
    uint4v w_;                                                               \
    w_.x = cvt2(ra[0].x, ra[0].y); w_.y = cvt2(ra[0].z, ra[0].w);            \
    w_.z = cvt2(ra[1].x, ra[1].y); w_.w = cvt2(ra[1].z, ra[1].w);            \
    DS_WRITE_B128(aWr + off_, w_);                                           \
  } while (0)

  // fragment read addressing: row = 64B; slot' = sl ^ ((fr>>1)&3)
  const int fr = lane & 15;
  const int sl = lane >> 4;
  const unsigned slotf = (unsigned)((sl ^ ((fr >> 1) & 3)) * 16);
  const int arow = wr * 64 + fr;
  const int brow = wc * 64 + fr;

  const unsigned aBase0 = lds_addr(&As[0][0]);
  const unsigned bBase0 = lds_addr(&Bs[0][0]);
  const unsigned aWr = aBase0 + (unsigned)(arow0 * 64)
                     + (unsigned)((((tid & 3) ^ ((tid >> 3) & 3)) * 16));

  short8 aqf[4], bqf[4];
  f32x4 acc[4][4] = {};

#define READ_FRAGS(ab_, bb_) do {                                            \
    _Pragma("unroll")                                                        \
    for (int mi = 0; mi < 4; ++mi)                                           \
      DS_READ_B128(aqf[mi], (ab_) + (unsigned)((arow + mi * 16) * 64) + slotf); \
    _Pragma("unroll")                                                        \
    for (int ni = 0; ni < 4; ++ni)                                           \
      DS_READ_B128(bqf[ni], (bb_) + (unsigned)((brow + ni * 16) * 64) + slotf); \
  } while (0)
#define MFMA_HALF(h_) do {                                                   \
    _Pragma("unroll")                                                        \
    for (int mi = 2 * (h_); mi < 2 * (h_) + 2; ++mi)                         \
      _Pragma("unroll")                                                      \
      for (int ni = 0; ni < 4; ++ni)                                         \
        acc[mi][ni] = __builtin_amdgcn_mfma_f32_16x16x32_bf16(               \
            aqf[mi], bqf[ni], acc[mi][ni], 0, 0, 0);                         \
  } while (0)

  // ---- prologue: A(0):2, B(0):2, B(1):2 -> vmcnt(2) drains A(0)+B(0),
  // leaves B(1); write A(0); load A(1) -> queue [B(1):2, A(1):2].
  LOAD_A();
  STAGE_B(0);
  STAGE_B(1);
  SCHED_FENCE();
  asm volatile("s_waitcnt vmcnt(2)");
  SCHED_FENCE();
  WRITE_A(0);
  LOAD_A();
  asm volatile("s_waitcnt lgkmcnt(0)");
  SCHED_FENCE();
  __builtin_amdgcn_s_barrier();

  for (int T = 0; T < NT; ++T) {
    const unsigned ab = aBase0 + ((T & 1) ? 8192u : 0u);
    const unsigned bb = bBase0 + ((T & 1) ? 16384u : 0u);

    // ---- p0: read all 8 frags; MFMA half 0.  (All reads of buf[T&1] drain
    // at lgkm(0) before the trailing barrier -> B(T+2) staging in p1 is safe.)
    READ_FRAGS(ab, bb);
    SCHED_FENCE();
    __builtin_amdgcn_s_barrier();
    asm volatile("s_waitcnt lgkmcnt(0)");
    SCHED_FENCE();
    __builtin_amdgcn_s_setprio(1);
    MFMA_HALF(0);
    __builtin_amdgcn_s_setprio(0);
    SCHED_FENCE();
    __builtin_amdgcn_s_barrier();

    // ---- p1: stage B(T+2); vmcnt(2) drains B(T+1)+A(T+1), leaves B(T+2);
    // write A(T+1); load A(T+2); MFMA half 1 (frags already in regs).
    if (T + 2 < NT) {
      STAGE_B(T + 2);
      SCHED_FENCE();
      asm volatile("s_waitcnt vmcnt(2)");
      SCHED_FENCE();
    } else if (T + 1 < NT) {
      SCHED_FENCE();
      asm volatile("s_waitcnt vmcnt(0)");
      SCHED_FENCE();
    }
    if (T + 1 < NT) {
      WRITE_A(T + 1);
      if (T + 2 < NT) LOAD_A();
    }
    SCHED_FENCE();
    __builtin_amdgcn_s_barrier();
    asm volatile("s_waitcnt lgkmcnt(0)");   // drain A ds_write
    SCHED_FENCE();
    __builtin_amdgcn_s_setprio(1);
    MFMA_HALF(1);
    __builtin_amdgcn_s_setprio(0);
    SCHED_FENCE();
    __builtin_amdgcn_s_barrier();
  }

  // epilogue: C/D layout col = lane&15, row = (lane>>4)*4 + q
  const int cc = lane & 15;
  const int crr = sl << 2;
#pragma unroll
  for (int ni = 0; ni < 4; ++ni) {
    int col = bn + wc * 64 + ni * 16 + cc;
    float bv = bias[col];
#pragma unroll
    for (int mi = 0; mi < 4; ++mi) {
      int row0 = bm + wr * 64 + mi * 16 + crr;
#pragma unroll
      for (int q = 0; q < 4; ++q)
        F[(size_t)(row0 + q) * DD + col] = f2bf(acc[mi][ni][q] + bv);
    }
  }
#undef READ_FRAGS
#undef MFMA_HALF
#undef STAGE_B
#undef LOAD_A
#undef WRITE_A
}

// ---------------------------------------------------------------------------
// Kernel 3: per (batch, t-half): Gram via MFMA -> d2 -> sims -> causal numer
// -> pow/normalize -> out.
// ---------------------------------------------------------------------------
__global__ __launch_bounds__(256) void k_batch_sims(const short* __restrict__ F,
                                                    const float* __restrict__ teach,
                                                    const float* __restrict__ cptr,
                                                    const float* __restrict__ gptr,
                                                    float* __restrict__ out) {
  __shared__ short ftile[128][40];
  __shared__ float simsT[64][129];
  __shared__ float sqv[128];
  __shared__ float sqp[256];
  __shared__ float teach_s[128][NC];
  __shared__ float numer[64][NC];
  __shared__ float rsum[64];

  const int b = blockIdx.x >> 1;
  const int half = blockIdx.x & 1;
  const int tid = threadIdx.x;
  const int lane = tid & 63;
  const int w = tid >> 6;
  const size_t fbase = (size_t)b * TT * DD;

  for (int idx = tid; idx < TT * NC; idx += 256)
    teach_s[idx / NC][idx % NC] = teach[(size_t)b * TT * NC + idx];

  {
    int row = tid >> 1;
    int kh = (tid & 1) << 9;
    const short* fp = F + fbase + (size_t)row * DD + kh;
    float s = 0.f;
    for (int k = 0; k < 512; k += 8) {
      short8 v = *reinterpret_cast<const short8*>(fp + k);
#pragma unroll
      for (int j = 0; j < 8; ++j) { float x = bf2f(v[j]); s += x * x; }
    }
    sqp[tid] = s;
  }
  __syncthreads();
  if (tid < 128) sqv[tid] = sqp[2 * tid] + sqp[2 * tid + 1];
  __syncthreads();

  f32x4 acc[2][4] = {};
  const int fr = lane & 15;
  const int fk = (lane >> 4) << 3;
  for (int k0 = 0; k0 < DD; k0 += 32) {
#pragma unroll
    for (int i = 0; i < 2; ++i) {
      int idx = tid + (i << 8);
      int row = idx >> 2;
      int kc = (idx & 3) << 3;
      short8 v = *reinterpret_cast<const short8*>(F + fbase + (size_t)row * DD + (k0 + kc));
      *reinterpret_cast<short8*>(&ftile[row][kc]) = v;
    }
    __syncthreads();
    short8 af[2], bfv[4];
#pragma unroll
    for (int mi = 0; mi < 2; ++mi)
      af[mi] = *reinterpret_cast<const short8*>(&ftile[w * 32 + mi * 16 + fr][fk]);
#pragma unroll
    for (int ni = 0; ni < 4; ++ni)
      bfv[ni] = *reinterpret_cast<const short8*>(&ftile[half * 64 + ni * 16 + fr][fk]);
#pragma unroll
    for (int mi = 0; mi < 2; ++mi)
#pragma unroll
      for (int ni = 0; ni < 4; ++ni)
        acc[mi][ni] = __builtin_amdgcn_mfma_f32_16x16x32_bf16(af[mi], bfv[ni], acc[mi][ni], 0, 0, 0);
    __syncthreads();
  }

  const float c0 = cptr[0];
  const int cc = lane & 15;
  const int crr = (lane >> 4) << 2;
#pragma unroll
  for (int mi = 0; mi < 2; ++mi) {
#pragma unroll
    for (int ni = 0; ni < 4; ++ni) {
#pragma unroll
      for (int q = 0; q < 4; ++q) {
        int s_g = w * 32 + mi * 16 + crr + q;
        int tl = ni * 16 + cc;
        int t_g = half * 64 + tl;
        float g = acc[mi][ni][q];
        float d2 = sqv[s_g] + sqv[t_g] - 2.0f * g;
        d2 = fmaxf(d2, EPS_D2_F);
        float dist = sqrtf(sqrtf(d2));
        simsT[tl][s_g] = (s_g < t_g) ? expf(-c0 * dist) : 0.0f;
      }
    }
  }
  __syncthreads();

  const float gam = gptr[0];
  for (int idx = tid; idx < 64 * NC; idx += 256) {
    int tl = idx / NC, c = idx % NC;
    float s = 0.f;
#pragma unroll 4
    for (int si = 0; si < TT; ++si)
      s += simsT[tl][si] * teach_s[si][c];
    float v = EPS_NUMER_F + s;
    numer[tl][c] = (gam == 1.0f) ? v : powf(v, gam);
  }
  __syncthreads();
  if (tid < 64) {
    float s = 0.f;
#pragma unroll
    for (int c = 0; c < NC; ++c) s += numer[tid][c];
    rsum[tid] = s;
  }
  __syncthreads();
  for (int idx = tid; idx < 64 * NC; idx += 256) {
    int tl = idx / NC, c = idx % NC;
    int t_g = half * 64 + tl;
    float v = numer[tl][c] / rsum[tl];
    if (t_g == 0) v = EPS_NUMER_F;
    out[(size_t)b * TT * NC + (size_t)t_g * NC + c] = v;
  }
}

// ---------------------------------------------------------------------------
extern "C" void kernel_launch(void* const* d_in, const int* in_sizes, int n_in,
                              void* d_out, int out_size, void* d_ws, size_t ws_size,
                              hipStream_t stream) {
  const float* data = (const float*)d_in[1];
  const float* teach = (const float*)d_in[2];
  const float* Wfe = (const float*)d_in[3];
  const float* bfe = (const float*)d_in[4];
  const float* cp = (const float*)d_in[5];
  const float* gp = (const float*)d_in[6];
  float* outp = (float*)d_out;

  char* ws = (char*)d_ws;
  short* Wt = (short*)ws;                             // @0:   6.29 MB
  short* F = (short*)(ws + (size_t)8 * 1024 * 1024);  // @8MB: 33.55 MB

  k_transpose_w<<<dim3(DD / 32, CHW / 32), 256, 0, stream>>>(Wfe, Wt);
  k_gemm_2cu<<<dim3((MM / 128) * (DD / 256)), 512, 0, stream>>>(data, Wt, bfe, F);
  k_batch_sims<<<dim3(BB * 2), 256, 0, stream>>>(F, teach, cp, gp, outp);
}